// Round 14
// baseline (115.298 us; speedup 1.0000x reference)
//
#include <hip/hip_runtime.h>
#include <math.h>

#define RR 512
#define RR2 (RR*RR)
#define PP 256
#define PP2 (PP*PP)

__constant__ double d_wls[3] = {4.6e-7, 5.4e-7, 6.2e-7};
__constant__ double d_dn[3]  = {0.52, 0.515, 0.51};

__device__ __forceinline__ float2 cadd(float2 a, float2 b){ return make_float2(a.x+b.x, a.y+b.y); }
__device__ __forceinline__ float2 csub(float2 a, float2 b){ return make_float2(a.x-b.x, a.y-b.y); }
__device__ __forceinline__ float2 cmulf(float2 a, float2 b){ return make_float2(a.x*b.x-a.y*b.y, a.x*b.y+a.y*b.x); }

// ======================================================================
// Wave-level FFT: N = 64 lanes x R regs, element n = lane + 64*reg.
// storage: out[lane + 64*m] = v[brR(m)]  ->  f(s) = (s>>6) + R_hi*bitrev6(s&63)
// ======================================================================

template<int R>
__device__ __forceinline__ void xf64_fwd(float2* v, int lane) {
  #pragma unroll
  for (int h = 32; h >= 1; h >>= 1) {
    float ang = -6.2831853071795865f * (float)(lane & (h-1)) / (float)(2*h);
    float sn, cs;
    __sincosf(ang, &sn, &cs);
    bool odd = (lane & h) != 0;
    float wc = odd ? cs : 1.f;
    float ws = odd ? sn : 0.f;
    #pragma unroll
    for (int r = 0; r < R; ++r) {
      float2 t;
      t.x = __shfl_xor(v[r].x, h);
      t.y = __shfl_xor(v[r].y, h);
      float2 d = odd ? csub(t, v[r]) : cadd(v[r], t);
      v[r] = make_float2(d.x*wc - d.y*ws, d.x*ws + d.y*wc);
    }
  }
}

template<int R>
__device__ __forceinline__ void xf64_inv(float2* v, int lane) {
  #pragma unroll
  for (int h = 1; h <= 32; h <<= 1) {
    float ang = 6.2831853071795865f * (float)(lane & (h-1)) / (float)(2*h);
    float sn, cs;
    __sincosf(ang, &sn, &cs);
    bool odd = (lane & h) != 0;
    #pragma unroll
    for (int r = 0; r < R; ++r) {
      float2 t;
      t.x = __shfl_xor(v[r].x, h);
      t.y = __shfl_xor(v[r].y, h);
      float2 s = odd ? v[r] : t;
      float2 ws = make_float2(s.x*cs - s.y*sn, s.x*sn + s.y*cs);
      v[r] = odd ? csub(t, ws) : cadd(v[r], ws);
    }
  }
}

template<bool INV>
__device__ __forceinline__ void reg_fft8(float2* a) {
  const float C = 0.70710678118654752f;
  {
    float2 t0 = csub(a[0], a[4]); a[0] = cadd(a[0], a[4]); a[4] = t0;
    float2 t1 = csub(a[1], a[5]); a[1] = cadd(a[1], a[5]);
    a[5] = INV ? make_float2(C*(t1.x - t1.y), C*(t1.x + t1.y))
               : make_float2(C*(t1.x + t1.y), C*(t1.y - t1.x));
    float2 t2 = csub(a[2], a[6]); a[2] = cadd(a[2], a[6]);
    a[6] = INV ? make_float2(-t2.y, t2.x) : make_float2(t2.y, -t2.x);
    float2 t3 = csub(a[3], a[7]); a[3] = cadd(a[3], a[7]);
    a[7] = INV ? make_float2(-C*(t3.x + t3.y), C*(t3.x - t3.y))
               : make_float2(C*(t3.y - t3.x), -C*(t3.x + t3.y));
  }
  #pragma unroll
  for (int g = 0; g < 2; ++g) {
    int b = g*4;
    float2 t0 = csub(a[b], a[b+2]); a[b] = cadd(a[b], a[b+2]); a[b+2] = t0;
    float2 t1 = csub(a[b+1], a[b+3]); a[b+1] = cadd(a[b+1], a[b+3]);
    a[b+3] = INV ? make_float2(-t1.y, t1.x) : make_float2(t1.y, -t1.x);
  }
  #pragma unroll
  for (int g = 0; g < 4; ++g) {
    int b = g*2;
    float2 t = csub(a[b], a[b+1]); a[b] = cadd(a[b], a[b+1]); a[b+1] = t;
  }
}

template<bool INV>
__device__ __forceinline__ void reg_fft4(float2* a) {
  float2 t0 = csub(a[0], a[2]); a[0] = cadd(a[0], a[2]); a[2] = t0;
  float2 t1 = csub(a[1], a[3]); a[1] = cadd(a[1], a[3]);
  a[3] = INV ? make_float2(-t1.y, t1.x) : make_float2(t1.y, -t1.x);
  t0 = csub(a[0], a[1]); a[0] = cadd(a[0], a[1]); a[1] = t0;
  t1 = csub(a[2], a[3]); a[2] = cadd(a[2], a[3]); a[3] = t1;
}

__device__ __forceinline__ void wfft512_fwd(float2* v, int lane) {
  const int BR3[8] = {0,4,2,6,1,5,3,7};
  reg_fft8<false>(v);
  float ang = -6.2831853071795865f * (float)lane * (1.f/512.f);
  float sn, cs; __sincosf(ang, &sn, &cs);
  float2 w1 = make_float2(cs, sn), w = w1;
  #pragma unroll
  for (int m = 1; m < 8; ++m) {
    v[BR3[m]] = cmulf(v[BR3[m]], w);
    if (m < 7) w = cmulf(w, w1);
  }
  xf64_fwd<8>(v, lane);
}

__device__ __forceinline__ void wfft512_inv(float2* v, int lane) {
  xf64_inv<8>(v, lane);
  float ang = 6.2831853071795865f * (float)lane * (1.f/512.f);
  float sn, cs; __sincosf(ang, &sn, &cs);
  float2 w1 = make_float2(cs, sn), w = w1;
  #pragma unroll
  for (int m = 1; m < 8; ++m) {
    v[m] = cmulf(v[m], w);
    if (m < 7) w = cmulf(w, w1);
  }
  reg_fft8<true>(v);
}

__device__ __forceinline__ void wfft256_fwd(float2* v, int lane) {
  const int BR2[4] = {0,2,1,3};
  reg_fft4<false>(v);
  float ang = -6.2831853071795865f * (float)lane * (1.f/256.f);
  float sn, cs; __sincosf(ang, &sn, &cs);
  float2 w1 = make_float2(cs, sn), w = w1;
  #pragma unroll
  for (int m = 1; m < 4; ++m) {
    v[BR2[m]] = cmulf(v[BR2[m]], w);
    if (m < 3) w = cmulf(w, w1);
  }
  xf64_fwd<4>(v, lane);
}

__device__ __forceinline__ void wfft256_inv(float2* v, int lane) {
  xf64_inv<4>(v, lane);
  float ang = 6.2831853071795865f * (float)lane * (1.f/256.f);
  float sn, cs; __sincosf(ang, &sn, &cs);
  float2 w1 = make_float2(cs, sn), w = w1;
  #pragma unroll
  for (int m = 1; m < 4; ++m) {
    v[m] = cmulf(v[m], w);
    if (m < 3) w = cmulf(w, w1);
  }
  reg_fft4<true>(v);
}

// ------------- merged setup: hm+field+rows-fwd, H phases, aux, packed X -------
__global__ __launch_bounds__(256) void k_setup(
    const float* __restrict__ zc, const float4* __restrict__ zv,
    float2* __restrict__ A, const float* __restrict__ mp,
    const float* __restrict__ cf, float* __restrict__ aux8,
    float* __restrict__ PH,
    const float* __restrict__ inp, float2* __restrict__ X) {
  int bid = blockIdx.x;
  if (bid < 256) {
    // hm rows 2b,2b+1 in LDS, then 6 field+rows-fwd tasks (3 bands x 2 rows)
    const int BR3[8] = {0,4,2,6,1,5,3,7};
    __shared__ float hmr[1024];
    int idx = bid * 256 + threadIdx.x;
    float4 s = make_float4(0.f,0.f,0.f,0.f);
    #pragma unroll 8
    for (int t = 0; t < 64; ++t) {
      float c = zc[t];
      float4 v = zv[(size_t)t * (RR2/4) + idx];
      s.x += c*v.x; s.y += c*v.y; s.z += c*v.z; s.w += c*v.w;
    }
    reinterpret_cast<float4*>(hmr)[threadIdx.x] = s;
    __syncthreads();
    int lane = threadIdx.x & 63, wv = threadIdx.x >> 6;
    for (int task = wv; task < 6; task += 4) {
      int band = task >> 1, rr = task & 1;
      int r = 2*bid + rr;
      float K = (float)(6.283185307179586 / d_wls[band] * d_dn[band]);
      int dx = r - 256;
      float2 v[8];
      #pragma unroll
      for (int m = 0; m < 8; ++m) {
        int col = lane + (m << 6);
        int dy = col - 256;
        float2 f = make_float2(0.f, 0.f);
        if (dx*dx + dy*dy < 65025) {
          float ph = K * hmr[rr*512 + col];
          float sn, cs;
          sincosf(ph, &sn, &cs);
          f = make_float2(cs, sn);
        }
        v[m] = f;
      }
      wfft512_fwd(v, lane);
      float2* row = A + (size_t)((band << 9) | r) * 512;
      #pragma unroll
      for (int m = 0; m < 8; ++m) row[lane + (m << 6)] = v[BR3[m]];
    }
  } else if (bid < 256 + 3072) {
    // H phases (permuted both dims). argd >= 0.986 for all bands -> no cutoff.
    int gid = (bid - 256) * 256 + threadIdx.x;   // 3 * RR2
    int band = gid >> 18, idx = gid & (RR2 - 1);
    double wl = d_wls[band];
    int su = idx >> 9, sv = idx & 511;
    int fui = (su >> 6) + 8 * (__brev(su & 63) >> 26);
    int fvi = (sv >> 6) + 8 * (__brev(sv & 63) >> 26);
    double inv_nd = 1.0 / (512.0 * 3.69e-6);
    double fu = (double)((fui < 256) ? fui : fui - 512) * inv_nd;
    double fv = (double)((fvi < 256) ? fvi : fvi - 512) * inv_nd;
    double au = wl * fu, av = wl * fv;
    double argd = 1.0 - au*au - av*av;
    double kz = (6.283185307179586 / wl) * sqrt(argd);
    PH[(size_t)(band*2    ) * RR2 + idx] = (float)fmod(0.047 * kz, 6.283185307179586);
    PH[(size_t)(band*2 + 1) * RR2 + idx] = (float)fmod(0.003 * kz, 6.283185307179586);
  } else if (bid == 256 + 3072) {
    int idx = threadIdx.x;
    if (idx >= 192) return;
    int l = idx % 3, j = (idx / 3) & 7, i = idx / 24;
    int i4 = (i < 4) ? i : 7 - i;
    int j4 = (j < 4) ? j : 7 - j;
    float s = 0.f;
    for (int f = 0; f < 4; ++f) s += cf[f*3 + l] * mp[f*16 + i4*4 + j4];
    aux8[idx] = s;
  } else {
    // packed input rows-fwd: z = x_{2g} + i*x_{2g+1}
    const int BR2[4] = {0,2,1,3};
    int b2 = bid - (256 + 3072 + 1);              // 0..767
    int lane = threadIdx.x & 63;
    int wid = (b2 << 2) | (threadIdx.x >> 6);     // p*256 + i, p = band*4+g
    int p = wid >> 8, i = wid & 255;
    int band = p >> 2, g = p & 3;
    const float* s0 = inp + (((size_t)(2*g)     * 256 + i) * 256) * 3 + band;
    const float* s1 = inp + (((size_t)(2*g + 1) * 256 + i) * 256) * 3 + band;
    float2 v[4];
    #pragma unroll
    for (int m = 0; m < 4; ++m) {
      int col = (lane + (m << 6)) * 3;
      v[m] = make_float2(s0[col], s1[col]);
    }
    wfft256_fwd(v, lane);
    float2* row = X + (size_t)wid * 256;
    #pragma unroll
    for (int m = 0; m < 4; ++m) row[lane + (m << 6)] = v[BR2[m]];
  }
}

// ===== mega_pre: cols-fwd + xH1(phase) + DFT8col + DFT8row -> Ahat (per strip)
__global__ __launch_bounds__(256) void k_mega_pre(
    const float2* __restrict__ A, const float* __restrict__ PH,
    float2* __restrict__ Ahat) {
  const int BR3[8] = {0,4,2,6,1,5,3,7};
  __shared__ float2 buf[512*9];
  int tid = threadIdx.x;
  int c8 = tid & 7, w32 = tid >> 3;
  int lane = tid & 63, wv = tid >> 6;
  int band = blockIdx.y;
  int col0 = blockIdx.x * 8;
  const float2* img = A + ((size_t)band << 18) + col0;
  #pragma unroll
  for (int r = w32; r < 512; r += 32) buf[r*9 + c8] = img[(size_t)r * 512 + c8];
  __syncthreads();
  const float* PH1 = PH + (((size_t)(band*2)) << 18);
  #pragma unroll
  for (int q = 0; q < 2; ++q) {
    int cc = wv*2 + q, scol = col0 + cc;
    float2 v[8];
    #pragma unroll
    for (int m = 0; m < 8; ++m) v[m] = buf[(lane + (m << 6))*9 + cc];
    wfft512_fwd(v, lane);
    const float* Prow = PH1 + (size_t)scol * 512;   // symmetric: row == column
    #pragma unroll
    for (int m = 0; m < 8; ++m) {
      float sn, cs;
      __sincosf(Prow[lane + (m << 6)], &sn, &cs);
      buf[(lane + (m << 6))*9 + cc] = cmulf(v[BR3[m]], make_float2(cs, sn));
    }
  }
  __syncthreads();
  // col-axis DFT8 (thread-per-row, in-place)
  #pragma unroll
  for (int r = tid; r < 512; r += 256) {
    float2 a[8];
    #pragma unroll
    for (int b = 0; b < 8; ++b) a[b] = buf[r*9 + BR3[b]];
    reg_fft8<true>(a);
    #pragma unroll
    for (int p = 0; p < 8; ++p) buf[r*9 + p] = a[p];
  }
  __syncthreads();
  // row-axis DFT8 (thread-per-(g,c), in-place)
  #pragma unroll
  for (int t2 = tid; t2 < 512; t2 += 256) {
    int g = t2 >> 3, c = t2 & 7;
    float2 a[8];
    #pragma unroll
    for (int b = 0; b < 8; ++b) a[b] = buf[(8*g + BR3[b])*9 + c];
    reg_fft8<true>(a);
    #pragma unroll
    for (int p = 0; p < 8; ++p) buf[(8*g + p)*9 + c] = a[p];
  }
  __syncthreads();
  float2* orow = Ahat + ((size_t)band << 18) + col0;
  #pragma unroll
  for (int r = w32; r < 512; r += 32) orow[(size_t)r * 512 + c8] = buf[r*9 + c8];
}

// ===== mega_post (per pm): mask-mult + IDFT8row + IDFT8col + xH2 + cols-inv ===
__global__ __launch_bounds__(256) void k_mega_post(
    const float2* __restrict__ Ahat, const float* __restrict__ PH,
    const float* __restrict__ aux8, float2* __restrict__ U) {
  const int BR3[8] = {0,4,2,6,1,5,3,7};
  __shared__ float2 buf[512*9];
  int tid = threadIdx.x;
  int c8 = tid & 7, w32 = tid >> 3;
  int lane = tid & 63, wv = tid >> 6;
  int band = blockIdx.y;
  int pm = blockIdx.z;
  int dr = pm >> 1, dc = pm & 1;
  int col0 = blockIdx.x * 8;
  const float2* img = Ahat + ((size_t)band << 18) + col0;
  #pragma unroll
  for (int r = w32; r < 512; r += 32) buf[r*9 + c8] = img[(size_t)r * 512 + c8];
  __syncthreads();
  // mask multiply + row-axis IDFT8 (thread-per-(g,c))
  #pragma unroll
  for (int t2 = tid; t2 < 512; t2 += 256) {
    int g = t2 >> 3, c = t2 & 7;
    int tc = BR3[c];
    int jm = ((tc + dc) & 7) * 3 + band;
    float2 a[8];
    #pragma unroll
    for (int p = 0; p < 8; ++p) a[p] = buf[(8*g + p)*9 + c];
    float2 nat[8];
    #pragma unroll
    for (int t = 0; t < 8; ++t) {
      float2 z = a[BR3[t]];
      float mv = aux8[((t + dr) & 7) * 24 + jm];
      nat[t] = make_float2(z.x*mv, z.y*mv);
    }
    reg_fft8<false>(nat);
    #pragma unroll
    for (int p = 0; p < 8; ++p) buf[(8*g + p)*9 + c] = nat[p];
  }
  __syncthreads();
  // col-axis IDFT8 (+1/64, thread-per-row)
  #pragma unroll
  for (int r = tid; r < 512; r += 256) {
    float2 nat[8];
    #pragma unroll
    for (int t = 0; t < 8; ++t) nat[t] = buf[r*9 + BR3[t]];
    reg_fft8<false>(nat);
    const float s64 = 1.f/64.f;
    #pragma unroll
    for (int p = 0; p < 8; ++p)
      buf[r*9 + p] = make_float2(nat[p].x*s64, nat[p].y*s64);
  }
  __syncthreads();
  // xH2 + wave col-inv
  const float* PH2 = PH + (((size_t)(band*2 + 1)) << 18);
  #pragma unroll
  for (int q = 0; q < 2; ++q) {
    int cc = wv*2 + q, scol = col0 + cc;
    const float* P2row = PH2 + (size_t)scol * 512;
    float2 u[8];
    #pragma unroll
    for (int m = 0; m < 8; ++m) {
      float sn, cs;
      __sincosf(P2row[lane + (m << 6)], &sn, &cs);
      u[m] = cmulf(buf[(lane + (m << 6))*9 + cc], make_float2(cs, sn));
    }
    wfft512_inv(u, lane);
    const float sc = 1.f/512.f;
    #pragma unroll
    for (int m = 0; m < 8; ++m) {
      float2 t = u[BR3[m]];
      buf[(lane + (m << 6))*9 + cc] = make_float2(t.x*sc, t.y*sc);
    }
  }
  __syncthreads();
  float2* orow = U + (((size_t)(band*4 + pm)) << 18) + col0;
  #pragma unroll
  for (int r = w32; r < 512; r += 32) orow[(size_t)r * 512 + c8] = buf[r*9 + c8];
}

// ------- wave rows-inv (row pair) + |.|^2 + 2x2 down + partial sum --
__global__ __launch_bounds__(256) void k_r512_inv_psf(
    const float2* __restrict__ U, float* __restrict__ PSF, float* __restrict__ PSUMP) {
  const int BR3[8] = {0,4,2,6,1,5,3,7};
  int lane = threadIdx.x & 63;
  int wid = (blockIdx.x << 2) | (threadIdx.x >> 6);   // p*256 + i
  int p = wid >> 8, i = wid & 255;
  const float2* row0 = U + ((size_t)p << 18) + (size_t)(2*i) * 512;
  const float2* row1 = row0 + 512;
  float2 v0[8], v1[8];
  #pragma unroll
  for (int m = 0; m < 8; ++m) v0[m] = row0[lane + (m << 6)];
  #pragma unroll
  for (int m = 0; m < 8; ++m) v1[m] = row1[lane + (m << 6)];
  wfft512_inv(v0, lane);
  wfft512_inv(v1, lane);
  float colsum[8];
  float tot = 0.f;
  #pragma unroll
  for (int pos = 0; pos < 8; ++pos) {
    float sq = v0[pos].x*v0[pos].x + v0[pos].y*v0[pos].y
             + v1[pos].x*v1[pos].x + v1[pos].y*v1[pos].y;
    tot += sq;
    colsum[pos] = sq;
  }
  const float sc2 = 0.25f / (512.f * 512.f);
  #pragma unroll
  for (int pos = 0; pos < 8; ++pos) {
    float pairs = colsum[pos] + __shfl_xor(colsum[pos], 1);
    if (!(lane & 1)) {
      int col = (lane >> 1) + (BR3[pos] << 5);
      PSF[((size_t)p << 16) | (i << 8) | col] = sc2 * pairs;
    }
  }
  #pragma unroll
  for (int h = 1; h < 64; h <<= 1) tot += __shfl_xor(tot, h);
  if (lane == 0) PSUMP[(p << 8) | i] = tot * sc2;
}

// --- wave rows-fwd fused with OTF load (shift + in-wave psum reduce + norm) ---
__global__ __launch_bounds__(256) void k_r256f_otf(
    const float* __restrict__ PSF, const float* __restrict__ PSUMP,
    float2* __restrict__ OTF) {
  const int BR2[4] = {0,2,1,3};
  int lane = threadIdx.x & 63;
  int wid = (blockIdx.x << 2) | (threadIdx.x >> 6);   // p*256 + i
  int p = wid >> 8, i = wid & 255;
  const float4* pp = reinterpret_cast<const float4*>(PSUMP + (p << 8));
  float4 q = pp[lane];
  float tot = (q.x + q.y) + (q.z + q.w);
  #pragma unroll
  for (int h = 1; h < 64; h <<= 1) tot += __shfl_xor(tot, h);
  float inv = 1.0f / tot;
  int si = (i + 128) & 255;
  const float* prow = PSF + ((size_t)p << 16) + (si << 8);
  float2 v[4];
  #pragma unroll
  for (int m = 0; m < 4; ++m) {
    int col = lane + (((m + 2) & 3) << 6);
    v[m] = make_float2(prow[col] * inv, 0.f);
  }
  wfft256_fwd(v, lane);
  float2* row = OTF + (size_t)wid * 256;
  #pragma unroll
  for (int m = 0; m < 4; ++m) row[lane + (m << 6)] = v[BR2[m]];
}

// ------- OTF cols-fwd (wave FFT, 1 col/wave) + parity S build; S COL-MAJOR ----
__global__ __launch_bounds__(256) void k_c256w(
    const float2* __restrict__ OTF, float2* __restrict__ Sb) {
  const int BR2[4] = {0,2,1,3};
  __shared__ float2 tile[256*5];
  int tid = threadIdx.x;
  int c = tid & 3, w = tid >> 2;
  int lane = tid & 63, wv = tid >> 6;
  int band = blockIdx.y;
  int col = blockIdx.x * 4 + c;
  float2 S0[4], S1[4], S2[4], S3[4];
  #pragma unroll
  for (int m = 0; m < 4; ++m) {
    S0[m] = make_float2(0.f,0.f); S1[m] = make_float2(0.f,0.f);
    S2[m] = make_float2(0.f,0.f); S3[m] = make_float2(0.f,0.f);
  }
  for (int q = 0; q < 4; ++q) {
    __syncthreads();
    const float2* img = OTF + (((size_t)(band*4 + q)) << 16) + col;
    #pragma unroll
    for (int r = w; r < 256; r += 64) tile[r*5 + c] = img[(size_t)r * 256];
    __syncthreads();
    float2 v[4];
    #pragma unroll
    for (int m = 0; m < 4; ++m) v[m] = tile[(lane + (m << 6))*5 + wv];
    wfft256_fwd(v, lane);
    float sg1 = (q & 1) ? -1.f : 1.f;
    float sg2 = (q & 2) ? -1.f : 1.f;
    float sg3 = sg1 * sg2;
    #pragma unroll
    for (int m = 0; m < 4; ++m) {
      float2 z = v[BR2[m]];
      S0[m] = cadd(S0[m], z);
      S1[m] = make_float2(S1[m].x + sg1*z.x, S1[m].y + sg1*z.y);
      S2[m] = make_float2(S2[m].x + sg2*z.x, S2[m].y + sg2*z.y);
      S3[m] = make_float2(S3[m].x + sg3*z.x, S3[m].y + sg3*z.y);
    }
  }
  // COL-MAJOR: S[plane][col][row]
  float2* S = Sb + (((size_t)(band*4)) << 16);
  #define WRITE_S(idx, arr)                                               \
  {                                                                       \
    __syncthreads();                                                      \
    _Pragma("unroll")                                                     \
    for (int m = 0; m < 4; ++m) tile[(lane + (m << 6))*5 + wv] = arr[m];  \
    __syncthreads();                                                      \
    _Pragma("unroll")                                                     \
    for (int r = w; r < 256; r += 64)                                     \
      S[((size_t)(idx) << 16) + (col << 8) + r] = tile[r*5 + c];          \
  }
  WRITE_S(0, S0)
  WRITE_S(1, S1)
  WRITE_S(2, S2)
  WRITE_S(3, S3)
  #undef WRITE_S
}

// --- fused: X cols-fwd (wave) + 9-tap combine (S col-major) + cols-inv ------
__global__ __launch_bounds__(256) void k_xyc(
    const float2* __restrict__ X, const float2* __restrict__ Sb,
    float2* __restrict__ Y) {
  const int BR2[4] = {0,2,1,3};
  const int CAm[4] = {3,2,0,1};
  const int CBm[4] = {2,3,1,0};
  __shared__ float2 Xl[256*9];
  int tid = threadIdx.x;
  int c = tid & 7, w = tid >> 3;
  int lane = tid & 63, wv = tid >> 6;
  int n = blockIdx.y;                            // packed plane: band*4 + g
  int band = n >> 2;
  int col0 = blockIdx.x * 8;
  const float2* Xn = X + ((size_t)n << 16);
  #pragma unroll
  for (int r = w; r < 256; r += 32) Xl[r*9 + c] = Xn[(r << 8) | (col0 + c)];
  __syncthreads();
  #pragma unroll
  for (int q = 0; q < 2; ++q) {
    int cc = wv*2 + q;
    float2 v[4];
    #pragma unroll
    for (int m = 0; m < 4; ++m) v[m] = Xl[(lane + (m << 6))*9 + cc];
    wfft256_fwd(v, lane);
    #pragma unroll
    for (int m = 0; m < 4; ++m) Xl[(lane + (m << 6))*9 + cc] = v[BR2[m]];
  }
  __syncthreads();
  const float2* S = Sb + (((size_t)(band*4)) << 16);
  float2 pa0[4], pa1[4];
  #define COMBINE(pa, qq)                                                       \
  {                                                                             \
    int cc = wv*2 + (qq);                                                       \
    int cA = (cc & 4) | CAm[cc & 3];                                            \
    int cB = (cc & 4) | CBm[cc & 3];                                            \
    int scol = col0 + cc;                                                       \
    _Pragma("unroll")                                                           \
    for (int m = 0; m < 4; ++m) {                                               \
      int u  = lane + (m << 6);                                                 \
      int ua = (u & ~3) | CAm[u & 3];                                           \
      int ub = (u & ~3) | CBm[u & 3];                                           \
      float2 X00 = Xl[u*9 + cc];                                                \
      float2 X01 = Xl[u*9 + cA],  X03 = Xl[u*9 + cB];                           \
      float2 X10 = Xl[ua*9 + cc], X30 = Xl[ub*9 + cc];                          \
      float2 X11 = Xl[ua*9 + cA], X13 = Xl[ua*9 + cB];                          \
      float2 X31 = Xl[ub*9 + cA], X33 = Xl[ub*9 + cB];                          \
      float2 t00 = make_float2(0.25f*X00.x, 0.25f*X00.y);                       \
      float2 t01 = make_float2(0.125f*(X01.x + X03.x - (X03.y - X01.y)),        \
                               0.125f*(X01.y + X03.y + (X03.x - X01.x)));       \
      float2 t10 = make_float2(0.125f*(X10.x + X30.x - (X30.y - X10.y)),        \
                               0.125f*(X10.y + X30.y + (X30.x - X10.x)));       \
      float2 t11 = make_float2(0.125f*(X13.x + X31.x - (X33.y - X11.y)),        \
                               0.125f*(X13.y + X31.y + (X33.x - X11.x)));       \
      int uv = (scol << 8) | u;               /* col-major S index */           \
      float2 acc = cmulf(S[uv], t00);                                           \
      acc = cadd(acc, cmulf(S[(1<<16) | uv], t01));                             \
      acc = cadd(acc, cmulf(S[(2<<16) | uv], t10));                             \
      acc = cadd(acc, cmulf(S[(3<<16) | uv], t11));                             \
      pa[m] = acc;                                                              \
    }                                                                           \
  }
  COMBINE(pa0, 0)
  COMBINE(pa1, 1)
  #undef COMBINE
  __syncthreads();
  const float sc = 1.f/256.f;
  wfft256_inv(pa0, lane);
  wfft256_inv(pa1, lane);
  #pragma unroll
  for (int pos = 0; pos < 4; ++pos) {
    int rown = lane + (BR2[pos] << 6);
    float2 a = pa0[pos], b = pa1[pos];
    Xl[rown*9 + wv*2]     = make_float2(a.x*sc, a.y*sc);
    Xl[rown*9 + wv*2 + 1] = make_float2(b.x*sc, b.y*sc);
  }
  __syncthreads();
  float2* Yn = Y + ((size_t)n << 16);
  #pragma unroll
  for (int r = w; r < 256; r += 32) Yn[(r << 8) | (col0 + c)] = Xl[r*9 + c];
}

// ----- wave rows-inv over 3 bands + color accumulate; PACKED (Re/Im = 2 imgs) -
__global__ __launch_bounds__(256) void k_r256_inv_accum3(
    const float2* __restrict__ Y, float* __restrict__ out,
    const float* __restrict__ cf) {
  const int BR2[4] = {0,2,1,3};
  int lane = threadIdx.x & 63;
  int wid = (blockIdx.x << 2) | (threadIdx.x >> 6);   // g*256 + i, g in [0,4)
  int g = wid >> 8, i = wid & 255;
  float aR0[4] = {0.f,0.f,0.f,0.f}, aG0[4] = {0.f,0.f,0.f,0.f}, aB0[4] = {0.f,0.f,0.f,0.f};
  float aR1[4] = {0.f,0.f,0.f,0.f}, aG1[4] = {0.f,0.f,0.f,0.f}, aB1[4] = {0.f,0.f,0.f,0.f};
  const float sc = 1.f/256.f;
  for (int band = 0; band < 3; ++band) {
    const float2* row = Y + (((size_t)(band*4 + g)) << 16) + ((size_t)i << 8);
    float2 v[4];
    #pragma unroll
    for (int m = 0; m < 4; ++m) v[m] = row[lane + (m << 6)];
    wfft256_inv(v, lane);
    float c0 = cf[band], c1 = cf[3 + band], c2 = cf[9 + band];
    #pragma unroll
    for (int pos = 0; pos < 4; ++pos) {
      float re = v[pos].x * sc;    // image 2g
      float im = v[pos].y * sc;    // image 2g+1
      int n2 = BR2[pos];
      aR0[n2] += c0*re; aG0[n2] += c1*re; aB0[n2] += c2*re;
      aR1[n2] += c0*im; aG1[n2] += c1*im; aB1[n2] += c2*im;
    }
  }
  #pragma unroll
  for (int n2 = 0; n2 < 4; ++n2) {
    int col = lane + (n2 << 6);
    float* o0 = out + (((size_t)(2*g)     * 256 + i) * 256 + col) * 3;
    float* o1 = out + (((size_t)(2*g + 1) * 256 + i) * 256 + col) * 3;
    o0[0] = aR0[n2]; o0[1] = aG0[n2]; o0[2] = aB0[n2];
    o1[0] = aR1[n2]; o1[1] = aG1[n2]; o1[2] = aB1[n2];
  }
}

// ================= host-side dispatch =================

extern "C" void kernel_launch(void* const* d_in, const int* in_sizes, int n_in,
                              void* d_out, int out_size, void* d_ws, size_t ws_size,
                              hipStream_t stream) {
  const float* inp = (const float*)d_in[0];
  const float* zc  = (const float*)d_in[1];
  const float* zv  = (const float*)d_in[2];
  const float* mp  = (const float*)d_in[3];
  const float* cf  = (const float*)d_in[4];
  float* out = (float*)d_out;

  char* ws = (char*)d_ws;
  size_t off = 0;
  auto alloc = [&](size_t bytes) -> void* {
    void* p = ws + off;
    off = (off + bytes + 255) & ~(size_t)255;
    return p;
  };
  float*  aux8  = (float*) alloc(256 * 4);
  float*  PSUMP = (float*) alloc((size_t)12 * 256 * 4);
  float2* A     = (float2*)alloc((size_t)3 * RR2 * 8);
  float2* Ahat  = (float2*)alloc((size_t)3 * RR2 * 8);
  float*  PH    = (float*) alloc((size_t)6 * RR2 * 4);
  float2* U     = (float2*)alloc((size_t)12 * RR2 * 8);
  float*  PSF   = (float*) alloc((size_t)12 * PP2 * 4);
  float2* OTF   = (float2*)alloc((size_t)12 * PP2 * 8);
  float2* Sb    = (float2*)alloc((size_t)12 * PP2 * 8);
  float2* X     = (float2*)alloc((size_t)12 * PP2 * 8);
  float2* Y     = (float2*)alloc((size_t)12 * PP2 * 8);

  // ---- merged setup: hm+field+rows-fwd(A) + H phases + aux + packed X ----
  k_setup<<<256 + 3072 + 1 + 768, 256, 0, stream>>>(zc, (const float4*)zv, A,
                                                    mp, cf, aux8, PH, inp, X);

  // ---- mega prefix (shared across pm): cols-fwd + xH1 + DFT8x8 -> Ahat ----
  k_mega_pre<<<dim3(64, 3), 256, 0, stream>>>(A, PH, Ahat);

  // ---- mega post (per pm): mask + IDFT8x8 + xH2 + cols-inv -> U ----
  k_mega_post<<<dim3(64, 3, 4), 256, 0, stream>>>(Ahat, PH, aux8, U);

  // ---- rows-inv + |.|^2 + downsample -> PSF ----
  k_r512_inv_psf<<<12*256/4, 256, 0, stream>>>(U, PSF, PSUMP);

  // ---- OTFs + parity S build ----
  k_r256f_otf<<<12*256/4, 256, 0, stream>>>(PSF, PSUMP, OTF);
  k_c256w<<<dim3(64, 3), 256, 0, stream>>>(OTF, Sb);

  // ---- convolution (packed pairs) ----
  k_xyc<<<dim3(32, 12), 256, 0, stream>>>(X, Sb, Y);
  k_r256_inv_accum3<<<4*256/4, 256, 0, stream>>>(Y, out, cf);
}

// Round 15
// 110.153 us; speedup vs baseline: 1.0467x; 1.0467x over previous
//
#include <hip/hip_runtime.h>
#include <math.h>

#define RR 512
#define RR2 (RR*RR)
#define PP 256
#define PP2 (PP*PP)

__constant__ double d_wls[3] = {4.6e-7, 5.4e-7, 6.2e-7};
__constant__ double d_dn[3]  = {0.52, 0.515, 0.51};

__device__ __forceinline__ float2 cadd(float2 a, float2 b){ return make_float2(a.x+b.x, a.y+b.y); }
__device__ __forceinline__ float2 csub(float2 a, float2 b){ return make_float2(a.x-b.x, a.y-b.y); }
__device__ __forceinline__ float2 cmulf(float2 a, float2 b){ return make_float2(a.x*b.x-a.y*b.y, a.x*b.y+a.y*b.x); }

// ======================================================================
// Wave-level FFT: N = 64 lanes x R regs, element n = lane + 64*reg.
// storage: out[lane + 64*m] = v[brR(m)]  ->  f(s) = (s>>6) + R_hi*bitrev6(s&63)
// ======================================================================

template<int R>
__device__ __forceinline__ void xf64_fwd(float2* v, int lane) {
  #pragma unroll
  for (int h = 32; h >= 1; h >>= 1) {
    float ang = -6.2831853071795865f * (float)(lane & (h-1)) / (float)(2*h);
    float sn, cs;
    __sincosf(ang, &sn, &cs);
    bool odd = (lane & h) != 0;
    float wc = odd ? cs : 1.f;
    float ws = odd ? sn : 0.f;
    #pragma unroll
    for (int r = 0; r < R; ++r) {
      float2 t;
      t.x = __shfl_xor(v[r].x, h);
      t.y = __shfl_xor(v[r].y, h);
      float2 d = odd ? csub(t, v[r]) : cadd(v[r], t);
      v[r] = make_float2(d.x*wc - d.y*ws, d.x*ws + d.y*wc);
    }
  }
}

template<int R>
__device__ __forceinline__ void xf64_inv(float2* v, int lane) {
  #pragma unroll
  for (int h = 1; h <= 32; h <<= 1) {
    float ang = 6.2831853071795865f * (float)(lane & (h-1)) / (float)(2*h);
    float sn, cs;
    __sincosf(ang, &sn, &cs);
    bool odd = (lane & h) != 0;
    #pragma unroll
    for (int r = 0; r < R; ++r) {
      float2 t;
      t.x = __shfl_xor(v[r].x, h);
      t.y = __shfl_xor(v[r].y, h);
      float2 s = odd ? v[r] : t;
      float2 ws = make_float2(s.x*cs - s.y*sn, s.x*sn + s.y*cs);
      v[r] = odd ? csub(t, ws) : cadd(v[r], ws);
    }
  }
}

template<bool INV>
__device__ __forceinline__ void reg_fft8(float2* a) {
  const float C = 0.70710678118654752f;
  {
    float2 t0 = csub(a[0], a[4]); a[0] = cadd(a[0], a[4]); a[4] = t0;
    float2 t1 = csub(a[1], a[5]); a[1] = cadd(a[1], a[5]);
    a[5] = INV ? make_float2(C*(t1.x - t1.y), C*(t1.x + t1.y))
               : make_float2(C*(t1.x + t1.y), C*(t1.y - t1.x));
    float2 t2 = csub(a[2], a[6]); a[2] = cadd(a[2], a[6]);
    a[6] = INV ? make_float2(-t2.y, t2.x) : make_float2(t2.y, -t2.x);
    float2 t3 = csub(a[3], a[7]); a[3] = cadd(a[3], a[7]);
    a[7] = INV ? make_float2(-C*(t3.x + t3.y), C*(t3.x - t3.y))
               : make_float2(C*(t3.y - t3.x), -C*(t3.x + t3.y));
  }
  #pragma unroll
  for (int g = 0; g < 2; ++g) {
    int b = g*4;
    float2 t0 = csub(a[b], a[b+2]); a[b] = cadd(a[b], a[b+2]); a[b+2] = t0;
    float2 t1 = csub(a[b+1], a[b+3]); a[b+1] = cadd(a[b+1], a[b+3]);
    a[b+3] = INV ? make_float2(-t1.y, t1.x) : make_float2(t1.y, -t1.x);
  }
  #pragma unroll
  for (int g = 0; g < 4; ++g) {
    int b = g*2;
    float2 t = csub(a[b], a[b+1]); a[b] = cadd(a[b], a[b+1]); a[b+1] = t;
  }
}

template<bool INV>
__device__ __forceinline__ void reg_fft4(float2* a) {
  float2 t0 = csub(a[0], a[2]); a[0] = cadd(a[0], a[2]); a[2] = t0;
  float2 t1 = csub(a[1], a[3]); a[1] = cadd(a[1], a[3]);
  a[3] = INV ? make_float2(-t1.y, t1.x) : make_float2(t1.y, -t1.x);
  t0 = csub(a[0], a[1]); a[0] = cadd(a[0], a[1]); a[1] = t0;
  t1 = csub(a[2], a[3]); a[2] = cadd(a[2], a[3]); a[3] = t1;
}

__device__ __forceinline__ void wfft512_fwd(float2* v, int lane) {
  const int BR3[8] = {0,4,2,6,1,5,3,7};
  reg_fft8<false>(v);
  float ang = -6.2831853071795865f * (float)lane * (1.f/512.f);
  float sn, cs; __sincosf(ang, &sn, &cs);
  float2 w1 = make_float2(cs, sn), w = w1;
  #pragma unroll
  for (int m = 1; m < 8; ++m) {
    v[BR3[m]] = cmulf(v[BR3[m]], w);
    if (m < 7) w = cmulf(w, w1);
  }
  xf64_fwd<8>(v, lane);
}

__device__ __forceinline__ void wfft512_inv(float2* v, int lane) {
  xf64_inv<8>(v, lane);
  float ang = 6.2831853071795865f * (float)lane * (1.f/512.f);
  float sn, cs; __sincosf(ang, &sn, &cs);
  float2 w1 = make_float2(cs, sn), w = w1;
  #pragma unroll
  for (int m = 1; m < 8; ++m) {
    v[m] = cmulf(v[m], w);
    if (m < 7) w = cmulf(w, w1);
  }
  reg_fft8<true>(v);
}

__device__ __forceinline__ void wfft256_fwd(float2* v, int lane) {
  const int BR2[4] = {0,2,1,3};
  reg_fft4<false>(v);
  float ang = -6.2831853071795865f * (float)lane * (1.f/256.f);
  float sn, cs; __sincosf(ang, &sn, &cs);
  float2 w1 = make_float2(cs, sn), w = w1;
  #pragma unroll
  for (int m = 1; m < 4; ++m) {
    v[BR2[m]] = cmulf(v[BR2[m]], w);
    if (m < 3) w = cmulf(w, w1);
  }
  xf64_fwd<4>(v, lane);
}

__device__ __forceinline__ void wfft256_inv(float2* v, int lane) {
  xf64_inv<4>(v, lane);
  float ang = 6.2831853071795865f * (float)lane * (1.f/256.f);
  float sn, cs; __sincosf(ang, &sn, &cs);
  float2 w1 = make_float2(cs, sn), w = w1;
  #pragma unroll
  for (int m = 1; m < 4; ++m) {
    v[m] = cmulf(v[m], w);
    if (m < 3) w = cmulf(w, w1);
  }
  reg_fft4<true>(v);
}

// ------------- merged setup: hm+field+rows-fwd, H phases, aux, packed X -------
__global__ __launch_bounds__(256) void k_setup(
    const float* __restrict__ zc, const float4* __restrict__ zv,
    float2* __restrict__ A, const float* __restrict__ mp,
    const float* __restrict__ cf, float* __restrict__ aux8,
    float* __restrict__ PH,
    const float* __restrict__ inp, float2* __restrict__ X) {
  int bid = blockIdx.x;
  if (bid < 256) {
    // hm rows 2b,2b+1 in LDS, then 6 field+rows-fwd tasks (3 bands x 2 rows)
    const int BR3[8] = {0,4,2,6,1,5,3,7};
    __shared__ float hmr[1024];
    int idx = bid * 256 + threadIdx.x;
    float4 s = make_float4(0.f,0.f,0.f,0.f);
    #pragma unroll 8
    for (int t = 0; t < 64; ++t) {
      float c = zc[t];
      float4 v = zv[(size_t)t * (RR2/4) + idx];
      s.x += c*v.x; s.y += c*v.y; s.z += c*v.z; s.w += c*v.w;
    }
    reinterpret_cast<float4*>(hmr)[threadIdx.x] = s;
    __syncthreads();
    int lane = threadIdx.x & 63, wv = threadIdx.x >> 6;
    for (int task = wv; task < 6; task += 4) {
      int band = task >> 1, rr = task & 1;
      int r = 2*bid + rr;
      float K = (float)(6.283185307179586 / d_wls[band] * d_dn[band]);
      int dx = r - 256;
      float2 v[8];
      #pragma unroll
      for (int m = 0; m < 8; ++m) {
        int col = lane + (m << 6);
        int dy = col - 256;
        float2 f = make_float2(0.f, 0.f);
        if (dx*dx + dy*dy < 65025) {
          float ph = K * hmr[rr*512 + col];
          float sn, cs;
          sincosf(ph, &sn, &cs);
          f = make_float2(cs, sn);
        }
        v[m] = f;
      }
      wfft512_fwd(v, lane);
      float2* row = A + (size_t)((band << 9) | r) * 512;
      #pragma unroll
      for (int m = 0; m < 8; ++m) row[lane + (m << 6)] = v[BR3[m]];
    }
  } else if (bid < 256 + 3072) {
    // H phases (permuted both dims). argd >= 0.986 for all bands -> no cutoff.
    int gid = (bid - 256) * 256 + threadIdx.x;   // 3 * RR2
    int band = gid >> 18, idx = gid & (RR2 - 1);
    double wl = d_wls[band];
    int su = idx >> 9, sv = idx & 511;
    int fui = (su >> 6) + 8 * (__brev(su & 63) >> 26);
    int fvi = (sv >> 6) + 8 * (__brev(sv & 63) >> 26);
    double inv_nd = 1.0 / (512.0 * 3.69e-6);
    double fu = (double)((fui < 256) ? fui : fui - 512) * inv_nd;
    double fv = (double)((fvi < 256) ? fvi : fvi - 512) * inv_nd;
    double au = wl * fu, av = wl * fv;
    double argd = 1.0 - au*au - av*av;
    double kz = (6.283185307179586 / wl) * sqrt(argd);
    PH[(size_t)(band*2    ) * RR2 + idx] = (float)fmod(0.047 * kz, 6.283185307179586);
    PH[(size_t)(band*2 + 1) * RR2 + idx] = (float)fmod(0.003 * kz, 6.283185307179586);
  } else if (bid == 256 + 3072) {
    int idx = threadIdx.x;
    if (idx >= 192) return;
    int l = idx % 3, j = (idx / 3) & 7, i = idx / 24;
    int i4 = (i < 4) ? i : 7 - i;
    int j4 = (j < 4) ? j : 7 - j;
    float s = 0.f;
    for (int f = 0; f < 4; ++f) s += cf[f*3 + l] * mp[f*16 + i4*4 + j4];
    aux8[idx] = s;
  } else {
    // packed input rows-fwd: z = x_{2g} + i*x_{2g+1}
    const int BR2[4] = {0,2,1,3};
    int b2 = bid - (256 + 3072 + 1);              // 0..767
    int lane = threadIdx.x & 63;
    int wid = (b2 << 2) | (threadIdx.x >> 6);     // p*256 + i, p = band*4+g
    int p = wid >> 8, i = wid & 255;
    int band = p >> 2, g = p & 3;
    const float* s0 = inp + (((size_t)(2*g)     * 256 + i) * 256) * 3 + band;
    const float* s1 = inp + (((size_t)(2*g + 1) * 256 + i) * 256) * 3 + band;
    float2 v[4];
    #pragma unroll
    for (int m = 0; m < 4; ++m) {
      int col = (lane + (m << 6)) * 3;
      v[m] = make_float2(s0[col], s1[col]);
    }
    wfft256_fwd(v, lane);
    float2* row = X + (size_t)wid * 256;
    #pragma unroll
    for (int m = 0; m < 4; ++m) row[lane + (m << 6)] = v[BR2[m]];
  }
}

// ===== mega (pm split across blockIdx.z, single in-place 36KB LDS buffer) =====
// cols-fwd + xH1(phase) + [DFT8x8 -> mask(dr,dc) -> IDFT8x8] + xH2(phase) + cols-inv
__global__ __launch_bounds__(256) void k_mega512(
    const float2* __restrict__ A, const float* __restrict__ PH,
    const float* __restrict__ aux8, float2* __restrict__ U) {
  const int BR3[8] = {0,4,2,6,1,5,3,7};
  __shared__ float2 buf[512*9];
  int tid = threadIdx.x;
  int c8 = tid & 7, w32 = tid >> 3;
  int lane = tid & 63, wv = tid >> 6;
  int band = blockIdx.y;
  int pm = blockIdx.z;
  int dr = pm >> 1, dc = pm & 1;
  int col0 = blockIdx.x * 8;
  const float2* img = A + ((size_t)band << 18) + col0;
  #pragma unroll
  for (int r = w32; r < 512; r += 32) buf[r*9 + c8] = img[(size_t)r * 512 + c8];
  __syncthreads();
  const float* PH1 = PH + (((size_t)(band*2)) << 18);
  #pragma unroll
  for (int q = 0; q < 2; ++q) {
    int cc = wv*2 + q, scol = col0 + cc;
    float2 v[8];
    #pragma unroll
    for (int m = 0; m < 8; ++m) v[m] = buf[(lane + (m << 6))*9 + cc];
    wfft512_fwd(v, lane);
    const float* Prow = PH1 + (size_t)scol * 512;   // symmetric: row == column
    #pragma unroll
    for (int m = 0; m < 8; ++m) {
      float sn, cs;
      __sincosf(Prow[lane + (m << 6)], &sn, &cs);
      buf[(lane + (m << 6))*9 + cc] = cmulf(v[BR3[m]], make_float2(cs, sn));
    }
  }
  __syncthreads();
  #pragma unroll
  for (int r = tid; r < 512; r += 256) {
    float2 a[8];
    #pragma unroll
    for (int b = 0; b < 8; ++b) a[b] = buf[r*9 + BR3[b]];
    reg_fft8<true>(a);
    #pragma unroll
    for (int p = 0; p < 8; ++p) buf[r*9 + p] = a[p];
  }
  __syncthreads();
  #pragma unroll
  for (int t2 = tid; t2 < 512; t2 += 256) {
    int g = t2 >> 3, c = t2 & 7;
    int tc = BR3[c];
    int jm = ((tc + dc) & 7) * 3 + band;
    float2 a[8];
    #pragma unroll
    for (int b = 0; b < 8; ++b) a[b] = buf[(8*g + BR3[b])*9 + c];
    reg_fft8<true>(a);
    float2 nat[8];
    #pragma unroll
    for (int t = 0; t < 8; ++t) {
      float2 z = a[BR3[t]];
      float mv = aux8[((t + dr) & 7) * 24 + jm];
      nat[t] = make_float2(z.x*mv, z.y*mv);
    }
    reg_fft8<false>(nat);
    #pragma unroll
    for (int p = 0; p < 8; ++p) buf[(8*g + p)*9 + c] = nat[p];
  }
  __syncthreads();
  #pragma unroll
  for (int r = tid; r < 512; r += 256) {
    float2 nat[8];
    #pragma unroll
    for (int t = 0; t < 8; ++t) nat[t] = buf[r*9 + BR3[t]];
    reg_fft8<false>(nat);
    const float s64 = 1.f/64.f;
    #pragma unroll
    for (int p = 0; p < 8; ++p)
      buf[r*9 + p] = make_float2(nat[p].x*s64, nat[p].y*s64);
  }
  __syncthreads();
  const float* PH2 = PH + (((size_t)(band*2 + 1)) << 18);
  #pragma unroll
  for (int q = 0; q < 2; ++q) {
    int cc = wv*2 + q, scol = col0 + cc;
    const float* P2row = PH2 + (size_t)scol * 512;
    float2 u[8];
    #pragma unroll
    for (int m = 0; m < 8; ++m) {
      float sn, cs;
      __sincosf(P2row[lane + (m << 6)], &sn, &cs);
      u[m] = cmulf(buf[(lane + (m << 6))*9 + cc], make_float2(cs, sn));
    }
    wfft512_inv(u, lane);
    const float sc = 1.f/512.f;
    #pragma unroll
    for (int m = 0; m < 8; ++m) {
      float2 t = u[BR3[m]];
      buf[(lane + (m << 6))*9 + cc] = make_float2(t.x*sc, t.y*sc);
    }
  }
  __syncthreads();
  float2* orow = U + (((size_t)(band*4 + pm)) << 18) + col0;
  #pragma unroll
  for (int r = w32; r < 512; r += 32) orow[(size_t)r * 512 + c8] = buf[r*9 + c8];
}

// ------- wave rows-inv (row pair) + |.|^2 + 2x2 down + partial sum --
__global__ __launch_bounds__(256) void k_r512_inv_psf(
    const float2* __restrict__ U, float* __restrict__ PSF, float* __restrict__ PSUMP) {
  const int BR3[8] = {0,4,2,6,1,5,3,7};
  int lane = threadIdx.x & 63;
  int wid = (blockIdx.x << 2) | (threadIdx.x >> 6);   // p*256 + i
  int p = wid >> 8, i = wid & 255;
  const float2* row0 = U + ((size_t)p << 18) + (size_t)(2*i) * 512;
  const float2* row1 = row0 + 512;
  float2 v0[8], v1[8];
  #pragma unroll
  for (int m = 0; m < 8; ++m) v0[m] = row0[lane + (m << 6)];
  #pragma unroll
  for (int m = 0; m < 8; ++m) v1[m] = row1[lane + (m << 6)];
  wfft512_inv(v0, lane);
  wfft512_inv(v1, lane);
  float colsum[8];
  float tot = 0.f;
  #pragma unroll
  for (int pos = 0; pos < 8; ++pos) {
    float sq = v0[pos].x*v0[pos].x + v0[pos].y*v0[pos].y
             + v1[pos].x*v1[pos].x + v1[pos].y*v1[pos].y;
    tot += sq;
    colsum[pos] = sq;
  }
  const float sc2 = 0.25f / (512.f * 512.f);
  #pragma unroll
  for (int pos = 0; pos < 8; ++pos) {
    float pairs = colsum[pos] + __shfl_xor(colsum[pos], 1);
    if (!(lane & 1)) {
      int col = (lane >> 1) + (BR3[pos] << 5);
      PSF[((size_t)p << 16) | (i << 8) | col] = sc2 * pairs;
    }
  }
  #pragma unroll
  for (int h = 1; h < 64; h <<= 1) tot += __shfl_xor(tot, h);
  if (lane == 0) PSUMP[(p << 8) | i] = tot * sc2;
}

// --- wave rows-fwd fused with OTF load (shift only; normalize moved to c256w) -
__global__ __launch_bounds__(256) void k_r256f_otf(
    const float* __restrict__ PSF, float2* __restrict__ OTF) {
  const int BR2[4] = {0,2,1,3};
  int lane = threadIdx.x & 63;
  int wid = (blockIdx.x << 2) | (threadIdx.x >> 6);   // p*256 + i
  int p = wid >> 8, i = wid & 255;
  int si = (i + 128) & 255;
  const float* prow = PSF + ((size_t)p << 16) + (si << 8);
  float2 v[4];
  #pragma unroll
  for (int m = 0; m < 4; ++m) {
    int col = lane + (((m + 2) & 3) << 6);
    v[m] = make_float2(prow[col], 0.f);
  }
  wfft256_fwd(v, lane);
  float2* row = OTF + (size_t)wid * 256;
  #pragma unroll
  for (int m = 0; m < 4; ++m) row[lane + (m << 6)] = v[BR2[m]];
}

// ------- OTF cols-fwd + per-plane normalize + parity S build; S COL-MAJOR ----
__global__ __launch_bounds__(256) void k_c256w(
    const float2* __restrict__ OTF, const float* __restrict__ PSUMP,
    float2* __restrict__ Sb) {
  const int BR2[4] = {0,2,1,3};
  __shared__ float2 tile[256*5];
  __shared__ float invq[4];
  int tid = threadIdx.x;
  int c = tid & 3, w = tid >> 2;
  int lane = tid & 63, wv = tid >> 6;
  int band = blockIdx.y;
  int col = blockIdx.x * 4 + c;
  // per-plane PSUM reduce: wave wv reduces plane band*4+wv (256 partials)
  {
    const float4* pp = reinterpret_cast<const float4*>(PSUMP + ((band*4 + wv) << 8));
    float4 q4 = pp[lane];
    float tot = (q4.x + q4.y) + (q4.z + q4.w);
    #pragma unroll
    for (int h = 1; h < 64; h <<= 1) tot += __shfl_xor(tot, h);
    if (lane == 0) invq[wv] = 1.0f / tot;
  }
  float2 S0[4], S1[4], S2[4], S3[4];
  #pragma unroll
  for (int m = 0; m < 4; ++m) {
    S0[m] = make_float2(0.f,0.f); S1[m] = make_float2(0.f,0.f);
    S2[m] = make_float2(0.f,0.f); S3[m] = make_float2(0.f,0.f);
  }
  for (int q = 0; q < 4; ++q) {
    __syncthreads();
    const float2* img = OTF + (((size_t)(band*4 + q)) << 16) + col;
    #pragma unroll
    for (int r = w; r < 256; r += 64) tile[r*5 + c] = img[(size_t)r * 256];
    __syncthreads();
    float inv = invq[q];
    float2 v[4];
    #pragma unroll
    for (int m = 0; m < 4; ++m) v[m] = tile[(lane + (m << 6))*5 + wv];
    wfft256_fwd(v, lane);
    float sg1 = ((q & 1) ? -1.f : 1.f) * inv;
    float sg2 = ((q & 2) ? -1.f : 1.f) * inv;
    float sg3 = ((q & 1) ? -1.f : 1.f) * ((q & 2) ? -1.f : 1.f) * inv;
    #pragma unroll
    for (int m = 0; m < 4; ++m) {
      float2 z = v[BR2[m]];
      S0[m] = make_float2(S0[m].x + inv*z.x, S0[m].y + inv*z.y);
      S1[m] = make_float2(S1[m].x + sg1*z.x, S1[m].y + sg1*z.y);
      S2[m] = make_float2(S2[m].x + sg2*z.x, S2[m].y + sg2*z.y);
      S3[m] = make_float2(S3[m].x + sg3*z.x, S3[m].y + sg3*z.y);
    }
  }
  // COL-MAJOR: S[plane][col][row]
  float2* S = Sb + (((size_t)(band*4)) << 16);
  #define WRITE_S(idx, arr)                                               \
  {                                                                       \
    __syncthreads();                                                      \
    _Pragma("unroll")                                                     \
    for (int m = 0; m < 4; ++m) tile[(lane + (m << 6))*5 + wv] = arr[m];  \
    __syncthreads();                                                      \
    _Pragma("unroll")                                                     \
    for (int r = w; r < 256; r += 64)                                     \
      S[((size_t)(idx) << 16) + (col << 8) + r] = tile[r*5 + c];          \
  }
  WRITE_S(0, S0)
  WRITE_S(1, S1)
  WRITE_S(2, S2)
  WRITE_S(3, S3)
  #undef WRITE_S
}

// --- fused: X cols-fwd (wave) + 9-tap combine (S col-major) + cols-inv ------
__global__ __launch_bounds__(256) void k_xyc(
    const float2* __restrict__ X, const float2* __restrict__ Sb,
    float2* __restrict__ Y) {
  const int BR2[4] = {0,2,1,3};
  const int CAm[4] = {3,2,0,1};
  const int CBm[4] = {2,3,1,0};
  __shared__ float2 Xl[256*9];
  int tid = threadIdx.x;
  int c = tid & 7, w = tid >> 3;
  int lane = tid & 63, wv = tid >> 6;
  int n = blockIdx.y;                            // packed plane: band*4 + g
  int band = n >> 2;
  int col0 = blockIdx.x * 8;
  const float2* Xn = X + ((size_t)n << 16);
  #pragma unroll
  for (int r = w; r < 256; r += 32) Xl[r*9 + c] = Xn[(r << 8) | (col0 + c)];
  __syncthreads();
  #pragma unroll
  for (int q = 0; q < 2; ++q) {
    int cc = wv*2 + q;
    float2 v[4];
    #pragma unroll
    for (int m = 0; m < 4; ++m) v[m] = Xl[(lane + (m << 6))*9 + cc];
    wfft256_fwd(v, lane);
    #pragma unroll
    for (int m = 0; m < 4; ++m) Xl[(lane + (m << 6))*9 + cc] = v[BR2[m]];
  }
  __syncthreads();
  const float2* S = Sb + (((size_t)(band*4)) << 16);
  float2 pa0[4], pa1[4];
  #define COMBINE(pa, qq)                                                       \
  {                                                                             \
    int cc = wv*2 + (qq);                                                       \
    int cA = (cc & 4) | CAm[cc & 3];                                            \
    int cB = (cc & 4) | CBm[cc & 3];                                            \
    int scol = col0 + cc;                                                       \
    _Pragma("unroll")                                                           \
    for (int m = 0; m < 4; ++m) {                                               \
      int u  = lane + (m << 6);                                                 \
      int ua = (u & ~3) | CAm[u & 3];                                           \
      int ub = (u & ~3) | CBm[u & 3];                                           \
      float2 X00 = Xl[u*9 + cc];                                                \
      float2 X01 = Xl[u*9 + cA],  X03 = Xl[u*9 + cB];                           \
      float2 X10 = Xl[ua*9 + cc], X30 = Xl[ub*9 + cc];                          \
      float2 X11 = Xl[ua*9 + cA], X13 = Xl[ua*9 + cB];                          \
      float2 X31 = Xl[ub*9 + cA], X33 = Xl[ub*9 + cB];                          \
      float2 t00 = make_float2(0.25f*X00.x, 0.25f*X00.y);                       \
      float2 t01 = make_float2(0.125f*(X01.x + X03.x - (X03.y - X01.y)),        \
                               0.125f*(X01.y + X03.y + (X03.x - X01.x)));       \
      float2 t10 = make_float2(0.125f*(X10.x + X30.x - (X30.y - X10.y)),        \
                               0.125f*(X10.y + X30.y + (X30.x - X10.x)));       \
      float2 t11 = make_float2(0.125f*(X13.x + X31.x - (X33.y - X11.y)),        \
                               0.125f*(X13.y + X31.y + (X33.x - X11.x)));       \
      int uv = (scol << 8) | u;               /* col-major S index */           \
      float2 acc = cmulf(S[uv], t00);                                           \
      acc = cadd(acc, cmulf(S[(1<<16) | uv], t01));                             \
      acc = cadd(acc, cmulf(S[(2<<16) | uv], t10));                             \
      acc = cadd(acc, cmulf(S[(3<<16) | uv], t11));                             \
      pa[m] = acc;                                                              \
    }                                                                           \
  }
  COMBINE(pa0, 0)
  COMBINE(pa1, 1)
  #undef COMBINE
  __syncthreads();
  const float sc = 1.f/256.f;
  wfft256_inv(pa0, lane);
  wfft256_inv(pa1, lane);
  #pragma unroll
  for (int pos = 0; pos < 4; ++pos) {
    int rown = lane + (BR2[pos] << 6);
    float2 a = pa0[pos], b = pa1[pos];
    Xl[rown*9 + wv*2]     = make_float2(a.x*sc, a.y*sc);
    Xl[rown*9 + wv*2 + 1] = make_float2(b.x*sc, b.y*sc);
  }
  __syncthreads();
  float2* Yn = Y + ((size_t)n << 16);
  #pragma unroll
  for (int r = w; r < 256; r += 32) Yn[(r << 8) | (col0 + c)] = Xl[r*9 + c];
}

// ----- wave rows-inv over 3 bands + color accumulate; PACKED (Re/Im = 2 imgs) -
__global__ __launch_bounds__(256) void k_r256_inv_accum3(
    const float2* __restrict__ Y, float* __restrict__ out,
    const float* __restrict__ cf) {
  const int BR2[4] = {0,2,1,3};
  int lane = threadIdx.x & 63;
  int wid = (blockIdx.x << 2) | (threadIdx.x >> 6);   // g*256 + i, g in [0,4)
  int g = wid >> 8, i = wid & 255;
  float aR0[4] = {0.f,0.f,0.f,0.f}, aG0[4] = {0.f,0.f,0.f,0.f}, aB0[4] = {0.f,0.f,0.f,0.f};
  float aR1[4] = {0.f,0.f,0.f,0.f}, aG1[4] = {0.f,0.f,0.f,0.f}, aB1[4] = {0.f,0.f,0.f,0.f};
  const float sc = 1.f/256.f;
  for (int band = 0; band < 3; ++band) {
    const float2* row = Y + (((size_t)(band*4 + g)) << 16) + ((size_t)i << 8);
    float2 v[4];
    #pragma unroll
    for (int m = 0; m < 4; ++m) v[m] = row[lane + (m << 6)];
    wfft256_inv(v, lane);
    float c0 = cf[band], c1 = cf[3 + band], c2 = cf[9 + band];
    #pragma unroll
    for (int pos = 0; pos < 4; ++pos) {
      float re = v[pos].x * sc;    // image 2g
      float im = v[pos].y * sc;    // image 2g+1
      int n2 = BR2[pos];
      aR0[n2] += c0*re; aG0[n2] += c1*re; aB0[n2] += c2*re;
      aR1[n2] += c0*im; aG1[n2] += c1*im; aB1[n2] += c2*im;
    }
  }
  #pragma unroll
  for (int n2 = 0; n2 < 4; ++n2) {
    int col = lane + (n2 << 6);
    float* o0 = out + (((size_t)(2*g)     * 256 + i) * 256 + col) * 3;
    float* o1 = out + (((size_t)(2*g + 1) * 256 + i) * 256 + col) * 3;
    o0[0] = aR0[n2]; o0[1] = aG0[n2]; o0[2] = aB0[n2];
    o1[0] = aR1[n2]; o1[1] = aG1[n2]; o1[2] = aB1[n2];
  }
}

// ================= host-side dispatch =================

extern "C" void kernel_launch(void* const* d_in, const int* in_sizes, int n_in,
                              void* d_out, int out_size, void* d_ws, size_t ws_size,
                              hipStream_t stream) {
  const float* inp = (const float*)d_in[0];
  const float* zc  = (const float*)d_in[1];
  const float* zv  = (const float*)d_in[2];
  const float* mp  = (const float*)d_in[3];
  const float* cf  = (const float*)d_in[4];
  float* out = (float*)d_out;

  char* ws = (char*)d_ws;
  size_t off = 0;
  auto alloc = [&](size_t bytes) -> void* {
    void* p = ws + off;
    off = (off + bytes + 255) & ~(size_t)255;
    return p;
  };
  float*  aux8  = (float*) alloc(256 * 4);
  float*  PSUMP = (float*) alloc((size_t)12 * 256 * 4);
  float2* A     = (float2*)alloc((size_t)3 * RR2 * 8);
  float*  PH    = (float*) alloc((size_t)6 * RR2 * 4);
  float2* U     = (float2*)alloc((size_t)12 * RR2 * 8);
  float*  PSF   = (float*) alloc((size_t)12 * PP2 * 4);
  float2* OTF   = (float2*)alloc((size_t)12 * PP2 * 8);
  float2* Sb    = (float2*)alloc((size_t)12 * PP2 * 8);
  float2* X     = (float2*)alloc((size_t)12 * PP2 * 8);
  float2* Y     = (float2*)alloc((size_t)12 * PP2 * 8);

  // ---- merged setup: hm+field+rows-fwd(A) + H phases + aux + packed X ----
  k_setup<<<256 + 3072 + 1 + 768, 256, 0, stream>>>(zc, (const float4*)zv, A,
                                                    mp, cf, aux8, PH, inp, X);

  // ---- mega (pm-split): cols-fwd + xH1 + freq-mask + xH2 + cols-inv -> U ----
  k_mega512<<<dim3(64, 3, 4), 256, 0, stream>>>(A, PH, aux8, U);

  // ---- rows-inv + |.|^2 + downsample -> PSF ----
  k_r512_inv_psf<<<12*256/4, 256, 0, stream>>>(U, PSF, PSUMP);

  // ---- OTFs (unnormalized) + normalize-in-S parity build ----
  k_r256f_otf<<<12*256/4, 256, 0, stream>>>(PSF, OTF);
  k_c256w<<<dim3(64, 3), 256, 0, stream>>>(OTF, PSUMP, Sb);

  // ---- convolution (packed pairs) ----
  k_xyc<<<dim3(32, 12), 256, 0, stream>>>(X, Sb, Y);
  k_r256_inv_accum3<<<4*256/4, 256, 0, stream>>>(Y, out, cf);
}

// Round 16
// 110.000 us; speedup vs baseline: 1.0482x; 1.0014x over previous
//
#include <hip/hip_runtime.h>
#include <math.h>

#define RR 512
#define RR2 (RR*RR)
#define PP 256
#define PP2 (PP*PP)

__constant__ double d_wls[3] = {4.6e-7, 5.4e-7, 6.2e-7};
__constant__ double d_dn[3]  = {0.52, 0.515, 0.51};

__device__ __forceinline__ float2 cadd(float2 a, float2 b){ return make_float2(a.x+b.x, a.y+b.y); }
__device__ __forceinline__ float2 csub(float2 a, float2 b){ return make_float2(a.x-b.x, a.y-b.y); }
__device__ __forceinline__ float2 cmulf(float2 a, float2 b){ return make_float2(a.x*b.x-a.y*b.y, a.x*b.y+a.y*b.x); }

// ======================================================================
// Wave-level FFT: N = 64 lanes x R regs, element n = lane + 64*reg.
// storage: out[lane + 64*m] = v[brR(m)]  ->  f(s) = (s>>6) + R_hi*bitrev6(s&63)
// ======================================================================

template<int R>
__device__ __forceinline__ void xf64_fwd(float2* v, int lane) {
  #pragma unroll
  for (int h = 32; h >= 1; h >>= 1) {
    float ang = -6.2831853071795865f * (float)(lane & (h-1)) / (float)(2*h);
    float sn, cs;
    __sincosf(ang, &sn, &cs);
    bool odd = (lane & h) != 0;
    float wc = odd ? cs : 1.f;
    float ws = odd ? sn : 0.f;
    #pragma unroll
    for (int r = 0; r < R; ++r) {
      float2 t;
      t.x = __shfl_xor(v[r].x, h);
      t.y = __shfl_xor(v[r].y, h);
      float2 d = odd ? csub(t, v[r]) : cadd(v[r], t);
      v[r] = make_float2(d.x*wc - d.y*ws, d.x*ws + d.y*wc);
    }
  }
}

template<int R>
__device__ __forceinline__ void xf64_inv(float2* v, int lane) {
  #pragma unroll
  for (int h = 1; h <= 32; h <<= 1) {
    float ang = 6.2831853071795865f * (float)(lane & (h-1)) / (float)(2*h);
    float sn, cs;
    __sincosf(ang, &sn, &cs);
    bool odd = (lane & h) != 0;
    #pragma unroll
    for (int r = 0; r < R; ++r) {
      float2 t;
      t.x = __shfl_xor(v[r].x, h);
      t.y = __shfl_xor(v[r].y, h);
      float2 s = odd ? v[r] : t;
      float2 ws = make_float2(s.x*cs - s.y*sn, s.x*sn + s.y*cs);
      v[r] = odd ? csub(t, ws) : cadd(v[r], ws);
    }
  }
}

template<bool INV>
__device__ __forceinline__ void reg_fft8(float2* a) {
  const float C = 0.70710678118654752f;
  {
    float2 t0 = csub(a[0], a[4]); a[0] = cadd(a[0], a[4]); a[4] = t0;
    float2 t1 = csub(a[1], a[5]); a[1] = cadd(a[1], a[5]);
    a[5] = INV ? make_float2(C*(t1.x - t1.y), C*(t1.x + t1.y))
               : make_float2(C*(t1.x + t1.y), C*(t1.y - t1.x));
    float2 t2 = csub(a[2], a[6]); a[2] = cadd(a[2], a[6]);
    a[6] = INV ? make_float2(-t2.y, t2.x) : make_float2(t2.y, -t2.x);
    float2 t3 = csub(a[3], a[7]); a[3] = cadd(a[3], a[7]);
    a[7] = INV ? make_float2(-C*(t3.x + t3.y), C*(t3.x - t3.y))
               : make_float2(C*(t3.y - t3.x), -C*(t3.x + t3.y));
  }
  #pragma unroll
  for (int g = 0; g < 2; ++g) {
    int b = g*4;
    float2 t0 = csub(a[b], a[b+2]); a[b] = cadd(a[b], a[b+2]); a[b+2] = t0;
    float2 t1 = csub(a[b+1], a[b+3]); a[b+1] = cadd(a[b+1], a[b+3]);
    a[b+3] = INV ? make_float2(-t1.y, t1.x) : make_float2(t1.y, -t1.x);
  }
  #pragma unroll
  for (int g = 0; g < 4; ++g) {
    int b = g*2;
    float2 t = csub(a[b], a[b+1]); a[b] = cadd(a[b], a[b+1]); a[b+1] = t;
  }
}

template<bool INV>
__device__ __forceinline__ void reg_fft4(float2* a) {
  float2 t0 = csub(a[0], a[2]); a[0] = cadd(a[0], a[2]); a[2] = t0;
  float2 t1 = csub(a[1], a[3]); a[1] = cadd(a[1], a[3]);
  a[3] = INV ? make_float2(-t1.y, t1.x) : make_float2(t1.y, -t1.x);
  t0 = csub(a[0], a[1]); a[0] = cadd(a[0], a[1]); a[1] = t0;
  t1 = csub(a[2], a[3]); a[2] = cadd(a[2], a[3]); a[3] = t1;
}

__device__ __forceinline__ void wfft512_fwd(float2* v, int lane) {
  const int BR3[8] = {0,4,2,6,1,5,3,7};
  reg_fft8<false>(v);
  float ang = -6.2831853071795865f * (float)lane * (1.f/512.f);
  float sn, cs; __sincosf(ang, &sn, &cs);
  float2 w1 = make_float2(cs, sn), w = w1;
  #pragma unroll
  for (int m = 1; m < 8; ++m) {
    v[BR3[m]] = cmulf(v[BR3[m]], w);
    if (m < 7) w = cmulf(w, w1);
  }
  xf64_fwd<8>(v, lane);
}

__device__ __forceinline__ void wfft512_inv(float2* v, int lane) {
  xf64_inv<8>(v, lane);
  float ang = 6.2831853071795865f * (float)lane * (1.f/512.f);
  float sn, cs; __sincosf(ang, &sn, &cs);
  float2 w1 = make_float2(cs, sn), w = w1;
  #pragma unroll
  for (int m = 1; m < 8; ++m) {
    v[m] = cmulf(v[m], w);
    if (m < 7) w = cmulf(w, w1);
  }
  reg_fft8<true>(v);
}

__device__ __forceinline__ void wfft256_fwd(float2* v, int lane) {
  const int BR2[4] = {0,2,1,3};
  reg_fft4<false>(v);
  float ang = -6.2831853071795865f * (float)lane * (1.f/256.f);
  float sn, cs; __sincosf(ang, &sn, &cs);
  float2 w1 = make_float2(cs, sn), w = w1;
  #pragma unroll
  for (int m = 1; m < 4; ++m) {
    v[BR2[m]] = cmulf(v[BR2[m]], w);
    if (m < 3) w = cmulf(w, w1);
  }
  xf64_fwd<4>(v, lane);
}

__device__ __forceinline__ void wfft256_inv(float2* v, int lane) {
  xf64_inv<4>(v, lane);
  float ang = 6.2831853071795865f * (float)lane * (1.f/256.f);
  float sn, cs; __sincosf(ang, &sn, &cs);
  float2 w1 = make_float2(cs, sn), w = w1;
  #pragma unroll
  for (int m = 1; m < 4; ++m) {
    v[m] = cmulf(v[m], w);
    if (m < 3) w = cmulf(w, w1);
  }
  reg_fft4<true>(v);
}

// ------------- merged setup: hm+field+rows-fwd, packed H phases, aux, X -------
__global__ __launch_bounds__(256) void k_setup(
    const float* __restrict__ zc, const float4* __restrict__ zv,
    float2* __restrict__ A, const float* __restrict__ mp,
    const float* __restrict__ cf, float* __restrict__ aux8,
    unsigned int* __restrict__ PH32,
    const float* __restrict__ inp, float2* __restrict__ X) {
  int bid = blockIdx.x;
  if (bid < 256) {
    // hm rows 2b,2b+1 in LDS, then 6 field+rows-fwd tasks (3 bands x 2 rows)
    const int BR3[8] = {0,4,2,6,1,5,3,7};
    __shared__ float hmr[1024];
    int idx = bid * 256 + threadIdx.x;
    float4 s = make_float4(0.f,0.f,0.f,0.f);
    #pragma unroll 8
    for (int t = 0; t < 64; ++t) {
      float c = zc[t];
      float4 v = zv[(size_t)t * (RR2/4) + idx];
      s.x += c*v.x; s.y += c*v.y; s.z += c*v.z; s.w += c*v.w;
    }
    reinterpret_cast<float4*>(hmr)[threadIdx.x] = s;
    __syncthreads();
    int lane = threadIdx.x & 63, wv = threadIdx.x >> 6;
    for (int task = wv; task < 6; task += 4) {
      int band = task >> 1, rr = task & 1;
      int r = 2*bid + rr;
      float K = (float)(6.283185307179586 / d_wls[band] * d_dn[band]);
      int dx = r - 256;
      float2 v[8];
      #pragma unroll
      for (int m = 0; m < 8; ++m) {
        int col = lane + (m << 6);
        int dy = col - 256;
        float2 f = make_float2(0.f, 0.f);
        if (dx*dx + dy*dy < 65025) {
          float ph = K * hmr[rr*512 + col];
          float sn, cs;
          sincosf(ph, &sn, &cs);
          f = make_float2(cs, sn);
        }
        v[m] = f;
      }
      wfft512_fwd(v, lane);
      float2* row = A + (size_t)((band << 9) | r) * 512;
      #pragma unroll
      for (int m = 0; m < 8; ++m) row[lane + (m << 6)] = v[BR3[m]];
    }
  } else if (bid < 256 + 3072) {
    // packed H phases as u16 fixed point (2pi/65536), both dists in one u32
    int gid = (bid - 256) * 256 + threadIdx.x;   // 3 * RR2
    int band = gid >> 18, idx = gid & (RR2 - 1);
    double wl = d_wls[band];
    int su = idx >> 9, sv = idx & 511;
    int fui = (su >> 6) + 8 * (__brev(su & 63) >> 26);
    int fvi = (sv >> 6) + 8 * (__brev(sv & 63) >> 26);
    double inv_nd = 1.0 / (512.0 * 3.69e-6);
    double fu = (double)((fui < 256) ? fui : fui - 512) * inv_nd;
    double fv = (double)((fvi < 256) ? fvi : fvi - 512) * inv_nd;
    double au = wl * fu, av = wl * fv;
    double argd = 1.0 - au*au - av*av;
    double kz = (6.283185307179586 / wl) * sqrt(argd);
    const double toq = 65536.0 / 6.283185307179586;
    unsigned int q0 = (unsigned int)(fmod(0.047 * kz, 6.283185307179586) * toq) & 0xffffu;
    unsigned int q1 = (unsigned int)(fmod(0.003 * kz, 6.283185307179586) * toq) & 0xffffu;
    PH32[(size_t)band * RR2 + idx] = q0 | (q1 << 16);
  } else if (bid == 256 + 3072) {
    int idx = threadIdx.x;
    if (idx >= 192) return;
    int l = idx % 3, j = (idx / 3) & 7, i = idx / 24;
    int i4 = (i < 4) ? i : 7 - i;
    int j4 = (j < 4) ? j : 7 - j;
    float s = 0.f;
    for (int f = 0; f < 4; ++f) s += cf[f*3 + l] * mp[f*16 + i4*4 + j4];
    aux8[idx] = s;
  } else {
    // packed input rows-fwd: z = x_{2g} + i*x_{2g+1}
    const int BR2[4] = {0,2,1,3};
    int b2 = bid - (256 + 3072 + 1);              // 0..767
    int lane = threadIdx.x & 63;
    int wid = (b2 << 2) | (threadIdx.x >> 6);     // p*256 + i, p = band*4+g
    int p = wid >> 8, i = wid & 255;
    int band = p >> 2, g = p & 3;
    const float* s0 = inp + (((size_t)(2*g)     * 256 + i) * 256) * 3 + band;
    const float* s1 = inp + (((size_t)(2*g + 1) * 256 + i) * 256) * 3 + band;
    float2 v[4];
    #pragma unroll
    for (int m = 0; m < 4; ++m) {
      int col = (lane + (m << 6)) * 3;
      v[m] = make_float2(s0[col], s1[col]);
    }
    wfft256_fwd(v, lane);
    float2* row = X + (size_t)wid * 256;
    #pragma unroll
    for (int m = 0; m < 4; ++m) row[lane + (m << 6)] = v[BR2[m]];
  }
}

// ===== mega (pm split across blockIdx.z, single in-place 36KB LDS buffer) =====
// cols-fwd + xH1 + [DFT8x8 -> mask(dr,dc) -> IDFT8x8] + xH2 + cols-inv
// H phases packed u16x2 in one u32, loaded ONCE and held in registers.
__global__ __launch_bounds__(256) void k_mega512(
    const float2* __restrict__ A, const unsigned int* __restrict__ PH32,
    const float* __restrict__ aux8, float2* __restrict__ U) {
  const int BR3[8] = {0,4,2,6,1,5,3,7};
  const float QSC = 6.2831853071795865f / 65536.f;
  __shared__ float2 buf[512*9];
  int tid = threadIdx.x;
  int c8 = tid & 7, w32 = tid >> 3;
  int lane = tid & 63, wv = tid >> 6;
  int band = blockIdx.y;
  int pm = blockIdx.z;
  int dr = pm >> 1, dc = pm & 1;
  int col0 = blockIdx.x * 8;
  const float2* img = A + ((size_t)band << 18) + col0;
  #pragma unroll
  for (int r = w32; r < 512; r += 32) buf[r*9 + c8] = img[(size_t)r * 512 + c8];
  __syncthreads();
  const unsigned int* PHb = PH32 + ((size_t)band << 18);
  unsigned int pw[2][8];
  #pragma unroll
  for (int q = 0; q < 2; ++q) {
    int cc = wv*2 + q, scol = col0 + cc;
    const unsigned int* Prow = PHb + (size_t)scol * 512;   // symmetric: row==col
    float2 v[8];
    #pragma unroll
    for (int m = 0; m < 8; ++m) {
      v[m] = buf[(lane + (m << 6))*9 + cc];
      pw[q][m] = Prow[lane + (m << 6)];
    }
    wfft512_fwd(v, lane);
    #pragma unroll
    for (int m = 0; m < 8; ++m) {
      float sn, cs;
      __sincosf((float)(pw[q][m] & 0xffffu) * QSC, &sn, &cs);
      buf[(lane + (m << 6))*9 + cc] = cmulf(v[BR3[m]], make_float2(cs, sn));
    }
  }
  __syncthreads();
  #pragma unroll
  for (int r = tid; r < 512; r += 256) {
    float2 a[8];
    #pragma unroll
    for (int b = 0; b < 8; ++b) a[b] = buf[r*9 + BR3[b]];
    reg_fft8<true>(a);
    #pragma unroll
    for (int p = 0; p < 8; ++p) buf[r*9 + p] = a[p];
  }
  __syncthreads();
  #pragma unroll
  for (int t2 = tid; t2 < 512; t2 += 256) {
    int g = t2 >> 3, c = t2 & 7;
    int tc = BR3[c];
    int jm = ((tc + dc) & 7) * 3 + band;
    float2 a[8];
    #pragma unroll
    for (int b = 0; b < 8; ++b) a[b] = buf[(8*g + BR3[b])*9 + c];
    reg_fft8<true>(a);
    float2 nat[8];
    #pragma unroll
    for (int t = 0; t < 8; ++t) {
      float2 z = a[BR3[t]];
      float mv = aux8[((t + dr) & 7) * 24 + jm];
      nat[t] = make_float2(z.x*mv, z.y*mv);
    }
    reg_fft8<false>(nat);
    #pragma unroll
    for (int p = 0; p < 8; ++p) buf[(8*g + p)*9 + c] = nat[p];
  }
  __syncthreads();
  #pragma unroll
  for (int r = tid; r < 512; r += 256) {
    float2 nat[8];
    #pragma unroll
    for (int t = 0; t < 8; ++t) nat[t] = buf[r*9 + BR3[t]];
    reg_fft8<false>(nat);
    const float s64 = 1.f/64.f;
    #pragma unroll
    for (int p = 0; p < 8; ++p)
      buf[r*9 + p] = make_float2(nat[p].x*s64, nat[p].y*s64);
  }
  __syncthreads();
  #pragma unroll
  for (int q = 0; q < 2; ++q) {
    int cc = wv*2 + q;
    float2 u[8];
    #pragma unroll
    for (int m = 0; m < 8; ++m) {
      float sn, cs;
      __sincosf((float)(pw[q][m] >> 16) * QSC, &sn, &cs);
      u[m] = cmulf(buf[(lane + (m << 6))*9 + cc], make_float2(cs, sn));
    }
    wfft512_inv(u, lane);
    const float sc = 1.f/512.f;
    #pragma unroll
    for (int m = 0; m < 8; ++m) {
      float2 t = u[BR3[m]];
      buf[(lane + (m << 6))*9 + cc] = make_float2(t.x*sc, t.y*sc);
    }
  }
  __syncthreads();
  float2* orow = U + (((size_t)(band*4 + pm)) << 18) + col0;
  #pragma unroll
  for (int r = w32; r < 512; r += 32) orow[(size_t)r * 512 + c8] = buf[r*9 + c8];
}

// ------- wave rows-inv (row pair) + |.|^2 + 2x2 down + partial sum --
__global__ __launch_bounds__(256) void k_r512_inv_psf(
    const float2* __restrict__ U, float* __restrict__ PSF, float* __restrict__ PSUMP) {
  const int BR3[8] = {0,4,2,6,1,5,3,7};
  int lane = threadIdx.x & 63;
  int wid = (blockIdx.x << 2) | (threadIdx.x >> 6);   // p*256 + i
  int p = wid >> 8, i = wid & 255;
  const float2* row0 = U + ((size_t)p << 18) + (size_t)(2*i) * 512;
  const float2* row1 = row0 + 512;
  float2 v0[8], v1[8];
  #pragma unroll
  for (int m = 0; m < 8; ++m) v0[m] = row0[lane + (m << 6)];
  #pragma unroll
  for (int m = 0; m < 8; ++m) v1[m] = row1[lane + (m << 6)];
  wfft512_inv(v0, lane);
  wfft512_inv(v1, lane);
  float colsum[8];
  float tot = 0.f;
  #pragma unroll
  for (int pos = 0; pos < 8; ++pos) {
    float sq = v0[pos].x*v0[pos].x + v0[pos].y*v0[pos].y
             + v1[pos].x*v1[pos].x + v1[pos].y*v1[pos].y;
    tot += sq;
    colsum[pos] = sq;
  }
  const float sc2 = 0.25f / (512.f * 512.f);
  #pragma unroll
  for (int pos = 0; pos < 8; ++pos) {
    float pairs = colsum[pos] + __shfl_xor(colsum[pos], 1);
    if (!(lane & 1)) {
      int col = (lane >> 1) + (BR3[pos] << 5);
      PSF[((size_t)p << 16) | (i << 8) | col] = sc2 * pairs;
    }
  }
  #pragma unroll
  for (int h = 1; h < 64; h <<= 1) tot += __shfl_xor(tot, h);
  if (lane == 0) PSUMP[(p << 8) | i] = tot * sc2;
}

// --- wave rows-fwd fused with OTF load (shift only; normalize in c256w) ---
__global__ __launch_bounds__(256) void k_r256f_otf(
    const float* __restrict__ PSF, float2* __restrict__ OTF) {
  const int BR2[4] = {0,2,1,3};
  int lane = threadIdx.x & 63;
  int wid = (blockIdx.x << 2) | (threadIdx.x >> 6);   // p*256 + i
  int p = wid >> 8, i = wid & 255;
  int si = (i + 128) & 255;
  const float* prow = PSF + ((size_t)p << 16) + (si << 8);
  float2 v[4];
  #pragma unroll
  for (int m = 0; m < 4; ++m) {
    int col = lane + (((m + 2) & 3) << 6);
    v[m] = make_float2(prow[col], 0.f);
  }
  wfft256_fwd(v, lane);
  float2* row = OTF + (size_t)wid * 256;
  #pragma unroll
  for (int m = 0; m < 4; ++m) row[lane + (m << 6)] = v[BR2[m]];
}

// ------- OTF cols-fwd + per-plane normalize + parity S build; S COL-MAJOR ----
__global__ __launch_bounds__(256) void k_c256w(
    const float2* __restrict__ OTF, const float* __restrict__ PSUMP,
    float2* __restrict__ Sb) {
  const int BR2[4] = {0,2,1,3};
  __shared__ float2 tile[256*5];
  __shared__ float invq[4];
  int tid = threadIdx.x;
  int c = tid & 3, w = tid >> 2;
  int lane = tid & 63, wv = tid >> 6;
  int band = blockIdx.y;
  int col = blockIdx.x * 4 + c;
  {
    const float4* pp = reinterpret_cast<const float4*>(PSUMP + ((band*4 + wv) << 8));
    float4 q4 = pp[lane];
    float tot = (q4.x + q4.y) + (q4.z + q4.w);
    #pragma unroll
    for (int h = 1; h < 64; h <<= 1) tot += __shfl_xor(tot, h);
    if (lane == 0) invq[wv] = 1.0f / tot;
  }
  float2 S0[4], S1[4], S2[4], S3[4];
  #pragma unroll
  for (int m = 0; m < 4; ++m) {
    S0[m] = make_float2(0.f,0.f); S1[m] = make_float2(0.f,0.f);
    S2[m] = make_float2(0.f,0.f); S3[m] = make_float2(0.f,0.f);
  }
  for (int q = 0; q < 4; ++q) {
    __syncthreads();
    const float2* img = OTF + (((size_t)(band*4 + q)) << 16) + col;
    #pragma unroll
    for (int r = w; r < 256; r += 64) tile[r*5 + c] = img[(size_t)r * 256];
    __syncthreads();
    float inv = invq[q];
    float2 v[4];
    #pragma unroll
    for (int m = 0; m < 4; ++m) v[m] = tile[(lane + (m << 6))*5 + wv];
    wfft256_fwd(v, lane);
    float sg1 = ((q & 1) ? -1.f : 1.f) * inv;
    float sg2 = ((q & 2) ? -1.f : 1.f) * inv;
    float sg3 = ((q & 1) ? -1.f : 1.f) * ((q & 2) ? -1.f : 1.f) * inv;
    #pragma unroll
    for (int m = 0; m < 4; ++m) {
      float2 z = v[BR2[m]];
      S0[m] = make_float2(S0[m].x + inv*z.x, S0[m].y + inv*z.y);
      S1[m] = make_float2(S1[m].x + sg1*z.x, S1[m].y + sg1*z.y);
      S2[m] = make_float2(S2[m].x + sg2*z.x, S2[m].y + sg2*z.y);
      S3[m] = make_float2(S3[m].x + sg3*z.x, S3[m].y + sg3*z.y);
    }
  }
  // COL-MAJOR: S[plane][col][row]
  float2* S = Sb + (((size_t)(band*4)) << 16);
  #define WRITE_S(idx, arr)                                               \
  {                                                                       \
    __syncthreads();                                                      \
    _Pragma("unroll")                                                     \
    for (int m = 0; m < 4; ++m) tile[(lane + (m << 6))*5 + wv] = arr[m];  \
    __syncthreads();                                                      \
    _Pragma("unroll")                                                     \
    for (int r = w; r < 256; r += 64)                                     \
      S[((size_t)(idx) << 16) + (col << 8) + r] = tile[r*5 + c];          \
  }
  WRITE_S(0, S0)
  WRITE_S(1, S1)
  WRITE_S(2, S2)
  WRITE_S(3, S3)
  #undef WRITE_S
}

// --- fused: X cols-fwd (wave) + 9-tap combine (S col-major) + cols-inv ------
__global__ __launch_bounds__(256) void k_xyc(
    const float2* __restrict__ X, const float2* __restrict__ Sb,
    float2* __restrict__ Y) {
  const int BR2[4] = {0,2,1,3};
  const int CAm[4] = {3,2,0,1};
  const int CBm[4] = {2,3,1,0};
  __shared__ float2 Xl[256*9];
  int tid = threadIdx.x;
  int c = tid & 7, w = tid >> 3;
  int lane = tid & 63, wv = tid >> 6;
  int n = blockIdx.y;                            // packed plane: band*4 + g
  int band = n >> 2;
  int col0 = blockIdx.x * 8;
  const float2* Xn = X + ((size_t)n << 16);
  #pragma unroll
  for (int r = w; r < 256; r += 32) Xl[r*9 + c] = Xn[(r << 8) | (col0 + c)];
  __syncthreads();
  #pragma unroll
  for (int q = 0; q < 2; ++q) {
    int cc = wv*2 + q;
    float2 v[4];
    #pragma unroll
    for (int m = 0; m < 4; ++m) v[m] = Xl[(lane + (m << 6))*9 + cc];
    wfft256_fwd(v, lane);
    #pragma unroll
    for (int m = 0; m < 4; ++m) Xl[(lane + (m << 6))*9 + cc] = v[BR2[m]];
  }
  __syncthreads();
  const float2* S = Sb + (((size_t)(band*4)) << 16);
  float2 pa0[4], pa1[4];
  #define COMBINE(pa, qq)                                                       \
  {                                                                             \
    int cc = wv*2 + (qq);                                                       \
    int cA = (cc & 4) | CAm[cc & 3];                                            \
    int cB = (cc & 4) | CBm[cc & 3];                                            \
    int scol = col0 + cc;                                                       \
    _Pragma("unroll")                                                           \
    for (int m = 0; m < 4; ++m) {                                               \
      int u  = lane + (m << 6);                                                 \
      int ua = (u & ~3) | CAm[u & 3];                                           \
      int ub = (u & ~3) | CBm[u & 3];                                           \
      float2 X00 = Xl[u*9 + cc];                                                \
      float2 X01 = Xl[u*9 + cA],  X03 = Xl[u*9 + cB];                           \
      float2 X10 = Xl[ua*9 + cc], X30 = Xl[ub*9 + cc];                          \
      float2 X11 = Xl[ua*9 + cA], X13 = Xl[ua*9 + cB];                          \
      float2 X31 = Xl[ub*9 + cA], X33 = Xl[ub*9 + cB];                          \
      float2 t00 = make_float2(0.25f*X00.x, 0.25f*X00.y);                       \
      float2 t01 = make_float2(0.125f*(X01.x + X03.x - (X03.y - X01.y)),        \
                               0.125f*(X01.y + X03.y + (X03.x - X01.x)));       \
      float2 t10 = make_float2(0.125f*(X10.x + X30.x - (X30.y - X10.y)),        \
                               0.125f*(X10.y + X30.y + (X30.x - X10.x)));       \
      float2 t11 = make_float2(0.125f*(X13.x + X31.x - (X33.y - X11.y)),        \
                               0.125f*(X13.y + X31.y + (X33.x - X11.x)));       \
      int uv = (scol << 8) | u;               /* col-major S index */           \
      float2 acc = cmulf(S[uv], t00);                                           \
      acc = cadd(acc, cmulf(S[(1<<16) | uv], t01));                             \
      acc = cadd(acc, cmulf(S[(2<<16) | uv], t10));                             \
      acc = cadd(acc, cmulf(S[(3<<16) | uv], t11));                             \
      pa[m] = acc;                                                              \
    }                                                                           \
  }
  COMBINE(pa0, 0)
  COMBINE(pa1, 1)
  #undef COMBINE
  __syncthreads();
  const float sc = 1.f/256.f;
  wfft256_inv(pa0, lane);
  wfft256_inv(pa1, lane);
  #pragma unroll
  for (int pos = 0; pos < 4; ++pos) {
    int rown = lane + (BR2[pos] << 6);
    float2 a = pa0[pos], b = pa1[pos];
    Xl[rown*9 + wv*2]     = make_float2(a.x*sc, a.y*sc);
    Xl[rown*9 + wv*2 + 1] = make_float2(b.x*sc, b.y*sc);
  }
  __syncthreads();
  float2* Yn = Y + ((size_t)n << 16);
  #pragma unroll
  for (int r = w; r < 256; r += 32) Yn[(r << 8) | (col0 + c)] = Xl[r*9 + c];
}

// ----- wave rows-inv over 3 bands + color accumulate; PACKED (Re/Im = 2 imgs) -
__global__ __launch_bounds__(256) void k_r256_inv_accum3(
    const float2* __restrict__ Y, float* __restrict__ out,
    const float* __restrict__ cf) {
  const int BR2[4] = {0,2,1,3};
  int lane = threadIdx.x & 63;
  int wid = (blockIdx.x << 2) | (threadIdx.x >> 6);   // g*256 + i, g in [0,4)
  int g = wid >> 8, i = wid & 255;
  float aR0[4] = {0.f,0.f,0.f,0.f}, aG0[4] = {0.f,0.f,0.f,0.f}, aB0[4] = {0.f,0.f,0.f,0.f};
  float aR1[4] = {0.f,0.f,0.f,0.f}, aG1[4] = {0.f,0.f,0.f,0.f}, aB1[4] = {0.f,0.f,0.f,0.f};
  const float sc = 1.f/256.f;
  for (int band = 0; band < 3; ++band) {
    const float2* row = Y + (((size_t)(band*4 + g)) << 16) + ((size_t)i << 8);
    float2 v[4];
    #pragma unroll
    for (int m = 0; m < 4; ++m) v[m] = row[lane + (m << 6)];
    wfft256_inv(v, lane);
    float c0 = cf[band], c1 = cf[3 + band], c2 = cf[9 + band];
    #pragma unroll
    for (int pos = 0; pos < 4; ++pos) {
      float re = v[pos].x * sc;    // image 2g
      float im = v[pos].y * sc;    // image 2g+1
      int n2 = BR2[pos];
      aR0[n2] += c0*re; aG0[n2] += c1*re; aB0[n2] += c2*re;
      aR1[n2] += c0*im; aG1[n2] += c1*im; aB1[n2] += c2*im;
    }
  }
  #pragma unroll
  for (int n2 = 0; n2 < 4; ++n2) {
    int col = lane + (n2 << 6);
    float* o0 = out + (((size_t)(2*g)     * 256 + i) * 256 + col) * 3;
    float* o1 = out + (((size_t)(2*g + 1) * 256 + i) * 256 + col) * 3;
    o0[0] = aR0[n2]; o0[1] = aG0[n2]; o0[2] = aB0[n2];
    o1[0] = aR1[n2]; o1[1] = aG1[n2]; o1[2] = aB1[n2];
  }
}

// ================= host-side dispatch =================

extern "C" void kernel_launch(void* const* d_in, const int* in_sizes, int n_in,
                              void* d_out, int out_size, void* d_ws, size_t ws_size,
                              hipStream_t stream) {
  const float* inp = (const float*)d_in[0];
  const float* zc  = (const float*)d_in[1];
  const float* zv  = (const float*)d_in[2];
  const float* mp  = (const float*)d_in[3];
  const float* cf  = (const float*)d_in[4];
  float* out = (float*)d_out;

  char* ws = (char*)d_ws;
  size_t off = 0;
  auto alloc = [&](size_t bytes) -> void* {
    void* p = ws + off;
    off = (off + bytes + 255) & ~(size_t)255;
    return p;
  };
  float*  aux8  = (float*) alloc(256 * 4);
  float*  PSUMP = (float*) alloc((size_t)12 * 256 * 4);
  float2* A     = (float2*)alloc((size_t)3 * RR2 * 8);
  unsigned int* PH32 = (unsigned int*)alloc((size_t)3 * RR2 * 4);
  float2* U     = (float2*)alloc((size_t)12 * RR2 * 8);
  float*  PSF   = (float*) alloc((size_t)12 * PP2 * 4);
  float2* OTF   = (float2*)alloc((size_t)12 * PP2 * 8);
  float2* Sb    = (float2*)alloc((size_t)12 * PP2 * 8);
  float2* X     = (float2*)alloc((size_t)12 * PP2 * 8);
  float2* Y     = (float2*)alloc((size_t)12 * PP2 * 8);

  // ---- merged setup: hm+field+rows-fwd(A) + packed H phases + aux + X ----
  k_setup<<<256 + 3072 + 1 + 768, 256, 0, stream>>>(zc, (const float4*)zv, A,
                                                    mp, cf, aux8, PH32, inp, X);

  // ---- mega (pm-split): cols-fwd + xH1 + freq-mask + xH2 + cols-inv -> U ----
  k_mega512<<<dim3(64, 3, 4), 256, 0, stream>>>(A, PH32, aux8, U);

  // ---- rows-inv + |.|^2 + downsample -> PSF ----
  k_r512_inv_psf<<<12*256/4, 256, 0, stream>>>(U, PSF, PSUMP);

  // ---- OTFs (unnormalized) + normalize-in-S parity build ----
  k_r256f_otf<<<12*256/4, 256, 0, stream>>>(PSF, OTF);
  k_c256w<<<dim3(64, 3), 256, 0, stream>>>(OTF, PSUMP, Sb);

  // ---- convolution (packed pairs) ----
  k_xyc<<<dim3(32, 12), 256, 0, stream>>>(X, Sb, Y);
  k_r256_inv_accum3<<<4*256/4, 256, 0, stream>>>(Y, out, cf);
}